// Round 2
// baseline (577.869 us; speedup 1.0000x reference)
//
#include <hip/hip_runtime.h>
#include <hip/hip_bf16.h>

#define N_NODES 50000
#define N_EDGES 800000
#define FDIM 64

// ---------------------------------------------------------------------------
// degree: deg[d] += 1 for each edge (float; exact for counts << 2^24)
// ---------------------------------------------------------------------------
__global__ void deg_kernel(const int* __restrict__ dst, float* __restrict__ deg) {
    int e = blockIdx.x * blockDim.x + threadIdx.x;
    if (e < N_EDGES) atomicAdd(&deg[dst[e]], 1.0f);
}

// ---------------------------------------------------------------------------
// scatter: accum[dst[e]][j] += x[src[e]][j]   (one wave per edge; lane = column)
// ---------------------------------------------------------------------------
__global__ void scatter_kernel(const int* __restrict__ src,
                               const int* __restrict__ dst,
                               const float* __restrict__ x,
                               float* __restrict__ accum) {
    int gid = blockIdx.x * blockDim.x + threadIdx.x;
    int e = gid >> 6;        // edge
    int j = gid & 63;        // column
    if (e < N_EDGES) {
        int s = src[e];
        int d = dst[e];
        float v = x[s * FDIM + j];
        atomicAdd(&accum[d * FDIM + j], v);
    }
}

// ---------------------------------------------------------------------------
// node kernel:  out = relu( ((accum + x)/(deg+1)) @ Wl + bl + x @ Wr )
// 256 threads = 4 nodes x 64 columns per iteration; weights staged in LDS
// ---------------------------------------------------------------------------
__global__ __launch_bounds__(256)
void sage_node_kernel(const float* __restrict__ x,
                      const float* __restrict__ accum,
                      const float* __restrict__ deg,
                      const float* __restrict__ Wl,
                      const float* __restrict__ bl,
                      const float* __restrict__ Wr,
                      float* __restrict__ out) {
    __shared__ float sWl[FDIM * FDIM];
    __shared__ float sWr[FDIM * FDIM];
    __shared__ float sbl[FDIM];
    __shared__ float sx[4][FDIM];
    __shared__ float sm[4][FDIM];

    for (int i = threadIdx.x; i < FDIM * FDIM; i += blockDim.x) {
        sWl[i] = Wl[i];
        sWr[i] = Wr[i];
    }
    if (threadIdx.x < FDIM) sbl[threadIdx.x] = bl[threadIdx.x];
    __syncthreads();

    const int g = threadIdx.x >> 6;   // node slot 0..3
    const int j = threadIdx.x & 63;   // output column

    for (int base = blockIdx.x * 4; base < N_NODES; base += gridDim.x * 4) {
        const int n = base + g;
        if (n < N_NODES) {
            float xv = x[n * FDIM + j];
            sx[g][j] = xv;
            sm[g][j] = (accum[n * FDIM + j] + xv) / (deg[n] + 1.0f);
        }
        __syncthreads();
        if (n < N_NODES) {
            float acc = sbl[j];
#pragma unroll
            for (int k = 0; k < FDIM; ++k) {
                acc = fmaf(sm[g][k], sWl[k * FDIM + j], acc);
                acc = fmaf(sx[g][k], sWr[k * FDIM + j], acc);
            }
            acc = fmaxf(acc, 0.0f);
            out[n * FDIM + j] = acc;
        }
        __syncthreads();
    }
}

// ---------------------------------------------------------------------------
extern "C" void kernel_launch(void* const* d_in, const int* in_sizes, int n_in,
                              void* d_out, int out_size, void* d_ws, size_t ws_size,
                              hipStream_t stream) {
    const float* x0  = (const float*)d_in[0];
    const int*   ei  = (const int*)d_in[1];
    const float* Wl0 = (const float*)d_in[2];
    const float* bl0 = (const float*)d_in[3];
    const float* Wr0 = (const float*)d_in[4];
    const float* Wl1 = (const float*)d_in[5];
    const float* bl1 = (const float*)d_in[6];
    const float* Wr1 = (const float*)d_in[7];
    float* out = (float*)d_out;

    const int* src = ei;            // edge_index[0]
    const int* dst = ei + N_EDGES;  // edge_index[1]

    // workspace layout (fp32): accum[N*64] | deg[N] | h1[N*64]  (~25.8 MB)
    float* accum = (float*)d_ws;
    float* deg   = accum + (size_t)N_NODES * FDIM;
    float* h1    = deg + N_NODES;

    // zero accum + deg
    hipMemsetAsync(accum, 0, ((size_t)N_NODES * FDIM + N_NODES) * sizeof(float), stream);

    // degree (shared by both layers)
    deg_kernel<<<(N_EDGES + 255) / 256, 256, 0, stream>>>(dst, deg);

    const int scatter_blocks = (N_EDGES * FDIM + 255) / 256;

    // ---- layer 0 ----
    scatter_kernel<<<scatter_blocks, 256, 0, stream>>>(src, dst, x0, accum);
    sage_node_kernel<<<2048, 256, 0, stream>>>(x0, accum, deg, Wl0, bl0, Wr0, h1);

    // ---- layer 1 ----
    hipMemsetAsync(accum, 0, (size_t)N_NODES * FDIM * sizeof(float), stream);
    scatter_kernel<<<scatter_blocks, 256, 0, stream>>>(src, dst, h1, accum);
    sage_node_kernel<<<2048, 256, 0, stream>>>(h1, accum, deg, Wl1, bl1, Wr1, out);
}

// Round 3
// 543.263 us; speedup vs baseline: 1.0637x; 1.0637x over previous
//
#include <hip/hip_runtime.h>
#include <hip/hip_bf16.h>

#define N_NODES 50000
#define N_EDGES 800000
#define FDIM 64

// ---------------------------------------------------------------------------
// CSR build step 1: in-degree counts (int atomics — cheap vs 51M float atomics)
// ---------------------------------------------------------------------------
__global__ void count_kernel(const int* __restrict__ dst, int* __restrict__ counts) {
    int e = blockIdx.x * blockDim.x + threadIdx.x;
    if (e < N_EDGES) atomicAdd(&counts[dst[e]], 1);
}

// ---------------------------------------------------------------------------
// CSR build step 2: exclusive prefix sum over counts -> row_start[0..N]
// single block, 1024 threads, wave-shfl scan (49 chunks)
// ---------------------------------------------------------------------------
__global__ __launch_bounds__(1024)
void scan_kernel(const int* __restrict__ counts, int* __restrict__ row_start) {
    __shared__ int wincl[16];
    __shared__ int s_carry;
    const int lane = threadIdx.x & 63;
    const int w = threadIdx.x >> 6;
    if (threadIdx.x == 0) s_carry = 0;
    __syncthreads();
    for (int base = 0; base < N_NODES; base += 1024) {
        int i = base + threadIdx.x;
        int v = (i < N_NODES) ? counts[i] : 0;
        int sv = v;
#pragma unroll
        for (int off = 1; off < 64; off <<= 1) {
            int t = __shfl_up(sv, off, 64);
            if (lane >= off) sv += t;
        }
        __shared__ int wtot[16];
        if (lane == 63) wtot[w] = sv;
        __syncthreads();
        if (w == 0) {
            int t = (lane < 16) ? wtot[lane] : 0;
#pragma unroll
            for (int off = 1; off < 16; off <<= 1) {
                int u = __shfl_up(t, off, 64);
                if (lane >= off) t += u;
            }
            if (lane < 16) wincl[lane] = t;
        }
        __syncthreads();
        int woff = (w == 0) ? 0 : wincl[w - 1];
        int excl = s_carry + woff + sv - v;
        if (i < N_NODES) row_start[i] = excl;
        __syncthreads();  // all reads of s_carry done
        if (threadIdx.x == 1023) s_carry += woff + sv;  // chunk total
        __syncthreads();
    }
    if (threadIdx.x == 0) row_start[N_NODES] = s_carry;
}

// ---------------------------------------------------------------------------
// CSR build step 3: cursor = row_start (running insert position per node)
// ---------------------------------------------------------------------------
__global__ void cursor_init_kernel(const int* __restrict__ row_start, int* __restrict__ cursor) {
    int i = blockIdx.x * blockDim.x + threadIdx.x;
    if (i < N_NODES) cursor[i] = row_start[i];
}

// ---------------------------------------------------------------------------
// CSR build step 4: bucket-fill sources by destination
// ---------------------------------------------------------------------------
__global__ void fill_kernel(const int* __restrict__ src, const int* __restrict__ dst,
                            int* __restrict__ cursor, int* __restrict__ csr_src) {
    int e = blockIdx.x * blockDim.x + threadIdx.x;
    if (e < N_EDGES) {
        int d = dst[e];
        int pos = atomicAdd(&cursor[d], 1);
        csr_src[pos] = src[e];
    }
}

// ---------------------------------------------------------------------------
// fused SAGE layer: one wave per node (lane = column).
// gather incoming rows (no atomics) -> mean -> LDS -> matmul with LDS weights
// out = relu( mean @ Wl + bl + x @ Wr )
// ---------------------------------------------------------------------------
__global__ __launch_bounds__(256)
void sage_layer_kernel(const float* __restrict__ x,
                       const int* __restrict__ row_start,
                       const int* __restrict__ csr_src,
                       const float* __restrict__ Wl,
                       const float* __restrict__ bl,
                       const float* __restrict__ Wr,
                       float* __restrict__ out) {
    __shared__ float sWl[FDIM * FDIM];
    __shared__ float sWr[FDIM * FDIM];
    __shared__ float sbl[FDIM];
    __shared__ __align__(16) float sm[4][FDIM];
    __shared__ __align__(16) float sx[4][FDIM];

    for (int i = threadIdx.x; i < FDIM * FDIM; i += 256) {
        sWl[i] = Wl[i];
        sWr[i] = Wr[i];
    }
    if (threadIdx.x < FDIM) sbl[threadIdx.x] = bl[threadIdx.x];
    __syncthreads();

    const int g = threadIdx.x >> 6;   // wave in block = node slot
    const int j = threadIdx.x & 63;   // column

    const int n = blockIdx.x * 4 + g;             // grid sized exactly: 12500*4 = 50000
    const int rs = row_start[n];
    const int re = row_start[n + 1];

    float xv = x[n * FDIM + j];                   // self-loop term
    float sum = xv;
    for (int e = rs; e < re; ++e) {
        int s = csr_src[e];                       // wave-uniform -> L1 broadcast
        sum += x[s * FDIM + j];                   // coalesced 256B row read
    }
    float mean = sum / (float)(re - rs + 1);

    sm[g][j] = mean;
    sx[g][j] = xv;
    __syncthreads();

    float acc = sbl[j];
#pragma unroll
    for (int k = 0; k < FDIM; k += 4) {
        float4 m4 = *(const float4*)&sm[g][k];    // ds_read_b128 broadcast
        float4 x4 = *(const float4*)&sx[g][k];
        acc = fmaf(m4.x, sWl[(k + 0) * FDIM + j], acc);
        acc = fmaf(x4.x, sWr[(k + 0) * FDIM + j], acc);
        acc = fmaf(m4.y, sWl[(k + 1) * FDIM + j], acc);
        acc = fmaf(x4.y, sWr[(k + 1) * FDIM + j], acc);
        acc = fmaf(m4.z, sWl[(k + 2) * FDIM + j], acc);
        acc = fmaf(x4.z, sWr[(k + 2) * FDIM + j], acc);
        acc = fmaf(m4.w, sWl[(k + 3) * FDIM + j], acc);
        acc = fmaf(x4.w, sWr[(k + 3) * FDIM + j], acc);
    }
    out[n * FDIM + j] = fmaxf(acc, 0.0f);
}

// ---------------------------------------------------------------------------
extern "C" void kernel_launch(void* const* d_in, const int* in_sizes, int n_in,
                              void* d_out, int out_size, void* d_ws, size_t ws_size,
                              hipStream_t stream) {
    const float* x0  = (const float*)d_in[0];
    const int*   ei  = (const int*)d_in[1];
    const float* Wl0 = (const float*)d_in[2];
    const float* bl0 = (const float*)d_in[3];
    const float* Wr0 = (const float*)d_in[4];
    const float* Wl1 = (const float*)d_in[5];
    const float* bl1 = (const float*)d_in[6];
    const float* Wr1 = (const float*)d_in[7];
    float* out = (float*)d_out;

    const int* src = ei;            // edge_index[0]
    const int* dst = ei + N_EDGES;  // edge_index[1]

    // workspace layout: counts[N] | row_start[N+1] | cursor[N] | csr_src[E] | h1[N*64]
    int* counts    = (int*)d_ws;
    int* row_start = counts + N_NODES;
    int* cursor    = row_start + N_NODES + 1;
    int* csr_src   = cursor + N_NODES;
    float* h1      = (float*)(csr_src + N_EDGES);

    hipMemsetAsync(counts, 0, N_NODES * sizeof(int), stream);
    count_kernel<<<(N_EDGES + 255) / 256, 256, 0, stream>>>(dst, counts);
    scan_kernel<<<1, 1024, 0, stream>>>(counts, row_start);
    cursor_init_kernel<<<(N_NODES + 255) / 256, 256, 0, stream>>>(row_start, cursor);
    fill_kernel<<<(N_EDGES + 255) / 256, 256, 0, stream>>>(src, dst, cursor, csr_src);

    // ---- layer 0 ----
    sage_layer_kernel<<<N_NODES / 4, 256, 0, stream>>>(x0, row_start, csr_src, Wl0, bl0, Wr0, h1);
    // ---- layer 1 ----
    sage_layer_kernel<<<N_NODES / 4, 256, 0, stream>>>(h1, row_start, csr_src, Wl1, bl1, Wr1, out);
}